// Round 4
// baseline (510.883 us; speedup 1.0000x reference)
//
#include <hip/hip_runtime.h>
#include <stdint.h>

namespace {
constexpr int Bn  = 16;
constexpr int Cc  = 256;
constexpr int Hn  = 512;
constexpr int Tn  = 4096;
constexpr int CWn = Cc / 32;   // 8 words packed over C
constexpr int HWn = Hn / 32;   // 16 words packed over H
constexpr int TWn = Tn / 32;   // 128 words packed over T
constexpr int TC  = 128;       // t-chunk per fused block
constexpr float EPSf = 1e-5f;
}

// ---------------- setup: thresholds + packed sign weights --------------------
// thr = mean - beta*sqrt(var+eps)/gamma  (gamma>=0 => bn(v)>0 <=> v>thr;
// gamma==0 gives +-inf which selects the constant sign(beta) branch correctly)
__global__ __launch_bounds__(256) void setup_kernel(
    const float* __restrict__ bn1g, const float* __restrict__ bn1b,
    const float* __restrict__ bn1m, const float* __restrict__ bn1v,
    const float* __restrict__ w1,
    const float* __restrict__ bn2g, const float* __restrict__ bn2b,
    const float* __restrict__ bn2m, const float* __restrict__ bn2v,
    const float* __restrict__ dww,
    const float* __restrict__ bn3g, const float* __restrict__ bn3b,
    const float* __restrict__ bn3m, const float* __restrict__ bn3v,
    const float* __restrict__ w2,
    float* __restrict__ thr1, float* __restrict__ thr2, float* __restrict__ thr3,
    uint32_t* __restrict__ dws, uint32_t* __restrict__ W1p, uint32_t* __restrict__ W2p)
{
  const int idx = blockIdx.x * 256 + threadIdx.x;  // 65536 threads
  if (idx < 8 * Hn * CWn) {                        // W1 words: 32768
    const int w = idx & (CWn - 1);
    const int h = idx >> 3;                        // global h 0..4095
    const float* src = w1 + (size_t)h * Cc + w * 32;
    uint32_t word = 0;
#pragma unroll
    for (int j = 0; j < 32; ++j) word |= (uint32_t)(src[j] > 0.f) << j;
    W1p[h * CWn + w] = word;
  } else {                                         // W2 words: 32768
    const int k = idx - 8 * Hn * CWn;
    const int w = k & (HWn - 1);
    const int c = k >> 4;                          // global c 0..2047
    const float* src = w2 + (size_t)c * Hn + w * 32;
    uint32_t word = 0;
#pragma unroll
    for (int j = 0; j < 32; ++j) word |= (uint32_t)(src[j] > 0.f) << j;
    W2p[c * HWn + w] = word;
  }
  if (idx < 8 * Cc)
    thr1[idx] = bn1m[idx] - bn1b[idx] * sqrtf(bn1v[idx] + EPSf) / bn1g[idx];
  if (idx < 8 * Hn) {
    thr2[idx] = bn2m[idx] - bn2b[idx] * sqrtf(bn2v[idx] + EPSf) / bn2g[idx];
    thr3[idx] = bn3m[idx] - bn3b[idx] * sqrtf(bn3v[idx] + EPSf) / bn3g[idx];
    uint32_t dw = 0;
    for (int k = 0; k < 3; ++k) dw |= (uint32_t)(dww[(size_t)idx * 3 + k] > 0.f) << k;
    dws[idx] = dw;
  }
}

// --------------- K1: bn1 + sign + pack over C  (x -> Xp), i=0 only -----------
__global__ __launch_bounds__(256) void k1_pack(
    const float* __restrict__ resid, const float* __restrict__ thr1,
    uint32_t* __restrict__ Xp)
{
  const int idx = blockIdx.x * 256 + threadIdx.x;  // Bn*CWn*Tn threads
  const int t  = idx & (Tn - 1);
  const int cw = (idx >> 12) & (CWn - 1);
  const int b  = idx >> 15;
  const float* r = resid + ((size_t)(b * Cc + cw * 32)) * Tn + t;
  uint32_t word = 0;
#pragma unroll
  for (int j = 0; j < 32; ++j)
    word |= (uint32_t)(r[(size_t)j * Tn] > thr1[cw * 32 + j]) << j;
  Xp[((size_t)b * CWn + cw) * Tn + t] = word;
}

// --------- K2: binary GEMM1 (C->H) + bn2 + sign + pack over T (-> Y) ---------
// Block-uniform (b, og, tblk) from blockIdx only => W1 rows scalarize to
// s_load/SGPRs; thread covers 8 output channels; lanes run over t.
// Y layout: [b][tw][h] so the dw-conv's lane-over-channel reads coalesce.
__global__ __launch_bounds__(256) void k2_gemm1(
    const uint32_t* __restrict__ Xp, const uint32_t* __restrict__ W1p,
    const float* __restrict__ thr2, uint32_t* __restrict__ Y)
{
  const int bid  = blockIdx.x;          // b(16) x og(64) x tblk(16)
  const int tblk = bid & 15;
  const int og   = (bid >> 4) & 63;
  const int b    = bid >> 10;
  const int t    = tblk * 256 + threadIdx.x;
  const int o    = og * 8;

  const uint32_t* xrow = Xp + (size_t)b * CWn * Tn + t;
  const uint32_t* wrow = W1p + o * CWn;     // uniform -> scalar loads
  int acc[8] = {0, 0, 0, 0, 0, 0, 0, 0};
#pragma unroll
  for (int w = 0; w < CWn; ++w) {
    const uint32_t xw = xrow[(size_t)w * Tn];
#pragma unroll
    for (int r = 0; r < 8; ++r)
      acc[r] += __popc(xw ^ wrow[r * CWn + w]);
  }
  const int lane = threadIdx.x & 63;
#pragma unroll
  for (int r = 0; r < 8; ++r) {
    const float v = (float)(Cc - 2 * acc[r]);
    const uint64_t m = __ballot(v > thr2[o + r]);   // bit l <-> lane l
    if ((lane & 31) == 0)
      Y[((size_t)b * TWn + (t >> 5)) * Hn + o + r] = (uint32_t)(m >> lane);
  }
}

// ---- K34: fused depthwise dilated conv (word-parallel, Z in LDS) + GEMM2 ----
// Block = 512 threads = (b, 128-t chunk).
// Phase A: 8 waves x 4 tasks cover 16 hw x 2 t-pairs; majority-logic dw-conv,
//          32x32 bit transpose, Z tile -> LDS [hw][t_local] (8 KB).
// Phase B: thread = (cw, 2 consecutive t); H->C binary GEMM with W2 in SGPRs,
//          float2 residual read/add/write, uint2 next-Xp pack (no ballot).
__global__ __launch_bounds__(512) void k34_fused(
    const uint32_t* __restrict__ Y, const uint32_t* __restrict__ dws,
    const float* __restrict__ thr3, const uint32_t* __restrict__ W2p,
    const float* __restrict__ rin, float* __restrict__ rout,
    const float* __restrict__ thr1n, uint32_t* __restrict__ Xp, int dil)
{
  __shared__ uint32_t Zlds[HWn * TC];   // [hw][t_local], 8 KB

  const int chunk = blockIdx.x & (Tn / TC - 1);   // 32 chunks
  const int b     = blockIdx.x >> 5;
  const int lane  = threadIdx.x & 63;
  const int wid   = threadIdx.x >> 6;             // 0..7
  const int lh    = lane & 31;
  const int tw0   = chunk * (TC / 32);            // global tw base (4 per chunk)

  // ---------------- Phase A: dw-conv into LDS ----------------
#pragma unroll
  for (int task = 0; task < 4; ++task) {
    const int tt    = wid * 4 + task;             // 0..31 = hw(16) x tpair(2)
    const int hw    = tt >> 1;
    const int tpair = tt & 1;
    const int tw    = tw0 + tpair * 2 + (lane >> 5);
    const int ch    = hw * 32 + lh;

    const uint32_t* yb = Y + (size_t)b * TWn * Hn + ch;
    const uint32_t ycur = yb[(size_t)tw * Hn];
    uint32_t yl, yr, Vl, Vr;
    if (dil >= 32) {
      const int dw = dil >> 5;
      const bool lok = tw >= dw, rok = tw + dw < TWn;
      yl = lok ? yb[(size_t)(tw - dw) * Hn] : 0u;
      yr = rok ? yb[(size_t)(tw + dw) * Hn] : 0u;
      Vl = lok ? ~0u : 0u;
      Vr = rok ? ~0u : 0u;
    } else {
      const uint32_t yp = (tw > 0) ? yb[(size_t)(tw - 1) * Hn] : 0u;
      const uint32_t yn = (tw < TWn - 1) ? yb[(size_t)(tw + 1) * Hn] : 0u;
      yl = (ycur << dil) | ((tw > 0) ? (yp >> (32 - dil)) : 0u);
      yr = (ycur >> dil) | ((tw < TWn - 1) ? (yn << (32 - dil)) : 0u);
      Vl = (tw == 0) ? (~0u << dil) : ~0u;
      Vr = (tw == TWn - 1) ? (~0u >> dil) : ~0u;
    }
    const uint32_t d = dws[ch];
    const uint32_t a  = ((d & 1u) ? yl : ~yl) & Vl;
    const uint32_t bb = (d & 2u) ? ycur : ~ycur;
    const uint32_t c  = ((d & 4u) ? yr : ~yr) & Vr;

    const float thr = thr3[ch];
    const float v3 = (thr + 3.f) * 0.5f;
    const float v2 = (thr + 2.f) * 0.5f;
    const int K3 = (int)(v3 >= 0.f) + (int)(v3 >= 1.f) + (int)(v3 >= 2.f) + (int)(v3 >= 3.f);
    const int K2 = (int)(v2 >= 0.f) + (int)(v2 >= 1.f) + (int)(v2 >= 2.f);

    const uint32_t g1 = a | bb | c;
    const uint32_t g2 = (a & bb) | (c & (a | bb));
    const uint32_t g3 = a & bb & c;
    const uint32_t full = (K3 == 0) ? ~0u : (K3 == 1) ? g1 : (K3 == 2) ? g2
                        : (K3 == 3) ? g3 : 0u;
    const uint32_t lm = (K2 == 0) ? ~0u : (K2 == 1) ? (bb | c) : (K2 == 2) ? (bb & c) : 0u;
    const uint32_t rm = (K2 == 0) ? ~0u : (K2 == 1) ? (a | bb) : (K2 == 2) ? (a & bb) : 0u;

    uint32_t w = (Vl & Vr & full) | (~Vl & lm) | (~Vr & rm);

    // 32x32 bit transpose within each half-wave: lane lh ends with the word
    // for t = tw*32+lh, bit j = channel hw*32+j.
#pragma unroll
    for (int s = 16; s; s >>= 1) {
      const uint32_t m = 0xFFFFFFFFu / ((1u << s) + 1u);
      const uint32_t o = __shfl_xor(w, s, 64);
      w = ((lane & s) == 0) ? ((w & m) | ((o & m) << s))
                            : ((w & ~m) | ((o & ~m) >> s));
    }
    Zlds[hw * TC + (tpair * 2 + (lane >> 5)) * 32 + lh] = w;
  }
  __syncthreads();

  // ---------------- Phase B: H->C GEMM + residual + next-X pack ----------------
  const int cw = threadIdx.x >> 6;                // 0..7 (block-uniform per wave)
  const int tl = (threadIdx.x & 63) * 2;          // 0..126
  const int tg = chunk * TC + tl;

  uint32_t z0[HWn], z1[HWn];
#pragma unroll
  for (int w = 0; w < HWn; ++w) {
    const uint32_t* p = &Zlds[w * TC + tl];
    z0[w] = p[0]; z1[w] = p[1];
  }

  const uint32_t* wrow = W2p + (cw * 32) * HWn;   // uniform -> scalar loads
  const size_t base = ((size_t)(b * Cc + cw * 32)) * Tn + tg;
  uint32_t word0 = 0, word1 = 0;
#pragma unroll 1
  for (int jo = 0; jo < 32; jo += 4) {
#pragma unroll
    for (int jj = 0; jj < 4; ++jj) {
      const int j = jo + jj;
      int a0 = 0, a1 = 0;
#pragma unroll
      for (int w = 0; w < HWn; ++w) {
        const uint32_t ww = wrow[j * HWn + w];
        a0 += __popc(z0[w] ^ ww);
        a1 += __popc(z1[w] ^ ww);
      }
      const float2 r = *(const float2*)&rin[base + (size_t)j * Tn];
      const float o0 = r.x + (float)(Hn - 2 * a0);
      const float o1 = r.y + (float)(Hn - 2 * a1);
      *(float2*)&rout[base + (size_t)j * Tn] = make_float2(o0, o1);
      const float th = thr1n[cw * 32 + j];
      word0 |= (uint32_t)(o0 > th) << j;
      word1 |= (uint32_t)(o1 > th) << j;
    }
  }
  uint2 xw; xw.x = word0; xw.y = word1;
  *(uint2*)&Xp[((size_t)b * CWn + cw) * Tn + tg] = xw;
}

// ----------------------------------------------------------------------------
extern "C" void kernel_launch(void* const* d_in, const int* in_sizes, int n_in,
                              void* d_out, int out_size, void* d_ws, size_t ws_size,
                              hipStream_t stream)
{
  const float* x     = (const float*)d_in[0];
  const float* bn1g  = (const float*)d_in[1];
  const float* bn1b  = (const float*)d_in[2];
  const float* bn1m  = (const float*)d_in[3];
  const float* bn1v  = (const float*)d_in[4];
  const float* w1    = (const float*)d_in[5];
  const float* bn2g  = (const float*)d_in[6];
  const float* bn2b  = (const float*)d_in[7];
  const float* bn2m  = (const float*)d_in[8];
  const float* bn2v  = (const float*)d_in[9];
  const float* dww   = (const float*)d_in[10];
  const float* bn3g  = (const float*)d_in[11];
  const float* bn3b  = (const float*)d_in[12];
  const float* bn3m  = (const float*)d_in[13];
  const float* bn3v  = (const float*)d_in[14];
  const float* w2    = (const float*)d_in[15];
  float* out = (float*)d_out;

  // workspace carve-up (~6.6 MB total)
  char* ws = (char*)d_ws;
  uint32_t* Xp  = (uint32_t*)(ws);                        // 2 MB
  uint32_t* Y   = (uint32_t*)(ws + (2u  << 20));          // 4 MB  [b][tw][h]
  uint32_t* W1p = (uint32_t*)(ws + (6u  << 20));          // 128 KB
  uint32_t* W2p = (uint32_t*)(ws + (6u  << 20) + (128u << 10)); // 128 KB
  float*    thr1 = (float*)(ws + (6u << 20) + (256u << 10));
  float*    thr2 = thr1 + 8 * Cc;
  float*    thr3 = thr2 + 8 * Hn;
  uint32_t* dws  = (uint32_t*)(thr3 + 8 * Hn);

  setup_kernel<<<256, 256, 0, stream>>>(bn1g, bn1b, bn1m, bn1v, w1,
                                        bn2g, bn2b, bn2m, bn2v, dww,
                                        bn3g, bn3b, bn3m, bn3v, w2,
                                        thr1, thr2, thr3, dws, W1p, W2p);

  k1_pack<<<2048, 256, 0, stream>>>(x, thr1, Xp);

  for (int i = 0; i < 8; ++i) {
    const float* rin = (i == 0) ? x : out;
    const int inext = (i < 7) ? i + 1 : 7;
    k2_gemm1 <<<16384, 256, 0, stream>>>(Xp, W1p + i * Hn * CWn, thr2 + i * Hn, Y);
    k34_fused<<<512,   512, 0, stream>>>(Y, dws + i * Hn, thr3 + i * Hn,
                                         W2p + i * Cc * HWn, rin, out,
                                         thr1 + inext * Cc, Xp, 1 << i);
  }
}

// Round 5
// 430.931 us; speedup vs baseline: 1.1855x; 1.1855x over previous
//
#include <hip/hip_runtime.h>
#include <stdint.h>

namespace {
constexpr int Bn  = 16;
constexpr int Cc  = 256;
constexpr int Hn  = 512;
constexpr int Tn  = 4096;
constexpr int CWn = Cc / 32;   // 8 words packed over C
constexpr int HWn = Hn / 32;   // 16 words packed over H
constexpr int TWn = Tn / 32;   // 128 words packed over T
constexpr int TC  = 64;        // t-chunk per fused block
constexpr float EPSf = 1e-5f;
}

// ---------------- setup: thresholds + packed sign weights --------------------
// thr = mean - beta*sqrt(var+eps)/gamma  (gamma>=0 => bn(v)>0 <=> v>thr;
// gamma==0 gives +-inf which selects the constant sign(beta) branch correctly)
__global__ __launch_bounds__(256) void setup_kernel(
    const float* __restrict__ bn1g, const float* __restrict__ bn1b,
    const float* __restrict__ bn1m, const float* __restrict__ bn1v,
    const float* __restrict__ w1,
    const float* __restrict__ bn2g, const float* __restrict__ bn2b,
    const float* __restrict__ bn2m, const float* __restrict__ bn2v,
    const float* __restrict__ dww,
    const float* __restrict__ bn3g, const float* __restrict__ bn3b,
    const float* __restrict__ bn3m, const float* __restrict__ bn3v,
    const float* __restrict__ w2,
    float* __restrict__ thr1, float* __restrict__ thr2, float* __restrict__ thr3,
    uint32_t* __restrict__ dws, uint32_t* __restrict__ W1p, uint32_t* __restrict__ W2p)
{
  const int idx = blockIdx.x * 256 + threadIdx.x;  // 65536 threads
  if (idx < 8 * Hn * CWn) {                        // W1 words: 32768
    const int w = idx & (CWn - 1);
    const int h = idx >> 3;                        // global h 0..4095
    const float* src = w1 + (size_t)h * Cc + w * 32;
    uint32_t word = 0;
#pragma unroll
    for (int j = 0; j < 32; ++j) word |= (uint32_t)(src[j] > 0.f) << j;
    W1p[h * CWn + w] = word;
  } else {                                         // W2 words: 32768
    const int k = idx - 8 * Hn * CWn;
    const int w = k & (HWn - 1);
    const int c = k >> 4;                          // global c 0..2047
    const float* src = w2 + (size_t)c * Hn + w * 32;
    uint32_t word = 0;
#pragma unroll
    for (int j = 0; j < 32; ++j) word |= (uint32_t)(src[j] > 0.f) << j;
    W2p[c * HWn + w] = word;
  }
  if (idx < 8 * Cc)
    thr1[idx] = bn1m[idx] - bn1b[idx] * sqrtf(bn1v[idx] + EPSf) / bn1g[idx];
  if (idx < 8 * Hn) {
    thr2[idx] = bn2m[idx] - bn2b[idx] * sqrtf(bn2v[idx] + EPSf) / bn2g[idx];
    thr3[idx] = bn3m[idx] - bn3b[idx] * sqrtf(bn3v[idx] + EPSf) / bn3g[idx];
    uint32_t dw = 0;
    for (int k = 0; k < 3; ++k) dw |= (uint32_t)(dww[(size_t)idx * 3 + k] > 0.f) << k;
    dws[idx] = dw;
  }
}

// --------------- K1: bn1 + sign + pack over C  (x -> Xp), i=0 only -----------
__global__ __launch_bounds__(256) void k1_pack(
    const float* __restrict__ resid, const float* __restrict__ thr1,
    uint32_t* __restrict__ Xp)
{
  const int idx = blockIdx.x * 256 + threadIdx.x;  // Bn*CWn*Tn threads
  const int t  = idx & (Tn - 1);
  const int cw = (idx >> 12) & (CWn - 1);
  const int b  = idx >> 15;
  const float* r = resid + ((size_t)(b * Cc + cw * 32)) * Tn + t;
  uint32_t word = 0;
#pragma unroll
  for (int j = 0; j < 32; ++j)
    word |= (uint32_t)(r[(size_t)j * Tn] > thr1[cw * 32 + j]) << j;
  Xp[((size_t)b * CWn + cw) * Tn + t] = word;
}

// --------- K2: binary GEMM1 (C->H) + bn2 + sign + pack over T (-> Y) ---------
// i=0 prologue only. Block-uniform (b, og, tblk) => W1 scalarizes to SGPRs.
// Y layout: [b][tw][h].
__global__ __launch_bounds__(256) void k2_gemm1(
    const uint32_t* __restrict__ Xp, const uint32_t* __restrict__ W1p,
    const float* __restrict__ thr2, uint32_t* __restrict__ Y)
{
  const int bid  = blockIdx.x;          // b(16) x og(64) x tblk(16)
  const int tblk = bid & 15;
  const int og   = (bid >> 4) & 63;
  const int b    = bid >> 10;
  const int t    = tblk * 256 + threadIdx.x;
  const int o    = og * 8;

  const uint32_t* xrow = Xp + (size_t)b * CWn * Tn + t;
  const uint32_t* wrow = W1p + o * CWn;     // uniform -> scalar loads
  int acc[8] = {0, 0, 0, 0, 0, 0, 0, 0};
#pragma unroll
  for (int w = 0; w < CWn; ++w) {
    const uint32_t xw = xrow[(size_t)w * Tn];
#pragma unroll
    for (int r = 0; r < 8; ++r)
      acc[r] += __popc(xw ^ wrow[r * CWn + w]);
  }
  const int lane = threadIdx.x & 63;
#pragma unroll
  for (int r = 0; r < 8; ++r) {
    const float v = (float)(Cc - 2 * acc[r]);
    const uint64_t m = __ballot(v > thr2[o + r]);   // bit l <-> lane l
    if ((lane & 31) == 0)
      Y[((size_t)b * TWn + (t >> 5)) * Hn + o + r] = (uint32_t)(m >> lane);
  }
}

// ---- K_iter: fused dwconv_i + GEMM2_i + residual + bn1/sign + GEMM1_{i+1} ----
// Block = 512 threads = (b, 64-t chunk); grid = 16*64 = 1024 blocks.
// Phase A: 8 waves x 2 tasks cover 16 hw; each half-wave does one 32ch x 32t
//          tile: majority-logic dwconv + 32x32 bit transpose -> Zlds[hw][tl].
// Phase B: wave = cw (readfirstlane => W2 in SGPRs), lane = t; H->C GEMM,
//          residual add (f32, reference order), next-block bn1/sign -> Xlds.
// Phase C: wave covers 64 outs (8 rounds x 8); X from Xlds, W1 in SGPRs;
//          ballot-pack Y_next[b][tw][h].
__global__ __launch_bounds__(512) void k_iter(
    const uint32_t* __restrict__ Yin, const uint32_t* __restrict__ dws,
    const float* __restrict__ thr3, const uint32_t* __restrict__ W2p,
    const float* __restrict__ rin, float* __restrict__ rout,
    const float* __restrict__ thr1n, const uint32_t* __restrict__ W1n,
    const float* __restrict__ thr2n, uint32_t* __restrict__ Yout,
    int dil, int do_next)
{
  __shared__ uint32_t Zlds[HWn * TC];   // [hw][t_local], 4 KB
  __shared__ uint32_t Xlds[CWn * TC];   // [cw][t_local], 2 KB

  const int chunk = blockIdx.x & (Tn / TC - 1);   // 64 chunks
  const int b     = blockIdx.x >> 6;
  const int lane  = threadIdx.x & 63;
  const int wid   = __builtin_amdgcn_readfirstlane(threadIdx.x >> 6); // 0..7
  const int lh    = lane & 31;
  const int twL   = lane >> 5;                    // 0/1: which tw of the chunk
  const int tw0   = chunk * 2;                    // 2 tw per chunk

  // ---------------- Phase A: dwconv into Zlds ----------------
#pragma unroll
  for (int task = 0; task < 2; ++task) {
    const int hw = wid * 2 + task;                // 0..15
    const int tw = tw0 + twL;
    const int ch = hw * 32 + lh;

    const uint32_t* yb = Yin + (size_t)b * TWn * Hn + ch;
    const uint32_t ycur = yb[(size_t)tw * Hn];
    uint32_t yl, yr, Vl, Vr;
    if (dil >= 32) {
      const int dw = dil >> 5;
      const bool lok = tw >= dw, rok = tw + dw < TWn;
      yl = lok ? yb[(size_t)(tw - dw) * Hn] : 0u;
      yr = rok ? yb[(size_t)(tw + dw) * Hn] : 0u;
      Vl = lok ? ~0u : 0u;
      Vr = rok ? ~0u : 0u;
    } else {
      const uint32_t yp = (tw > 0) ? yb[(size_t)(tw - 1) * Hn] : 0u;
      const uint32_t yn = (tw < TWn - 1) ? yb[(size_t)(tw + 1) * Hn] : 0u;
      yl = (ycur << dil) | ((tw > 0) ? (yp >> (32 - dil)) : 0u);
      yr = (ycur >> dil) | ((tw < TWn - 1) ? (yn << (32 - dil)) : 0u);
      Vl = (tw == 0) ? (~0u << dil) : ~0u;
      Vr = (tw == TWn - 1) ? (~0u >> dil) : ~0u;
    }
    const uint32_t d = dws[ch];
    const uint32_t a  = ((d & 1u) ? yl : ~yl) & Vl;
    const uint32_t bb = (d & 2u) ? ycur : ~ycur;
    const uint32_t c  = ((d & 4u) ? yr : ~yr) & Vr;

    const float thr = thr3[ch];
    const float v3 = (thr + 3.f) * 0.5f;
    const float v2 = (thr + 2.f) * 0.5f;
    const int K3 = (int)(v3 >= 0.f) + (int)(v3 >= 1.f) + (int)(v3 >= 2.f) + (int)(v3 >= 3.f);
    const int K2 = (int)(v2 >= 0.f) + (int)(v2 >= 1.f) + (int)(v2 >= 2.f);

    const uint32_t g1 = a | bb | c;
    const uint32_t g2 = (a & bb) | (c & (a | bb));
    const uint32_t g3 = a & bb & c;
    const uint32_t full = (K3 == 0) ? ~0u : (K3 == 1) ? g1 : (K3 == 2) ? g2
                        : (K3 == 3) ? g3 : 0u;
    const uint32_t lm = (K2 == 0) ? ~0u : (K2 == 1) ? (bb | c) : (K2 == 2) ? (bb & c) : 0u;
    const uint32_t rm = (K2 == 0) ? ~0u : (K2 == 1) ? (a | bb) : (K2 == 2) ? (a & bb) : 0u;

    uint32_t w = (Vl & Vr & full) | (~Vl & lm) | (~Vr & rm);

    // 32x32 bit transpose within each 32-lane half (s<=16 stays in-half):
    // lane lh ends with word for t=tw*32+lh, bit j = channel hw*32+j.
#pragma unroll
    for (int s = 16; s; s >>= 1) {
      const uint32_t m = 0xFFFFFFFFu / ((1u << s) + 1u);
      const uint32_t o = __shfl_xor(w, s, 64);
      w = ((lane & s) == 0) ? ((w & m) | ((o & m) << s))
                            : ((w & ~m) | ((o & ~m) >> s));
    }
    Zlds[hw * TC + twL * 32 + lh] = w;
  }
  __syncthreads();

  // ------ Phase B: H->C GEMM + residual + bn1/sign for next block ------
  {
    const int cw = wid;                 // SGPR (readfirstlane above)
    const int tl = lane;
    const int tg = chunk * TC + tl;

    uint32_t z[HWn];
#pragma unroll
    for (int w = 0; w < HWn; ++w) z[w] = Zlds[w * TC + tl];

    const uint32_t* wrow = W2p + (cw * 32) * HWn;   // uniform -> scalar loads
    const size_t base = ((size_t)(b * Cc + cw * 32)) * Tn + tg;
    uint32_t word = 0;
#pragma unroll 1
    for (int jo = 0; jo < 32; jo += 4) {
#pragma unroll
      for (int jj = 0; jj < 4; ++jj) {
        const int j = jo + jj;
        int acc = 0;
#pragma unroll
        for (int w = 0; w < HWn; ++w) acc += __popc(z[w] ^ wrow[j * HWn + w]);
        const float ro = rin[base + (size_t)j * Tn] + (float)(Hn - 2 * acc);
        rout[base + (size_t)j * Tn] = ro;
        word |= (uint32_t)(ro > thr1n[cw * 32 + j]) << j;
      }
    }
    Xlds[cw * TC + tl] = word;
  }
  __syncthreads();

  // ------ Phase C: GEMM1 for next block (C->H) -> Yout bits ------
  if (do_next) {
    const int t  = chunk * TC + lane;
    uint32_t x[CWn];
#pragma unroll
    for (int w = 0; w < CWn; ++w) x[w] = Xlds[w * TC + lane];

#pragma unroll 1
    for (int r = 0; r < 8; ++r) {
      const int o = wid * 64 + r * 8;               // SGPR-uniform
      const uint32_t* wrow = W1n + o * CWn;         // -> scalar loads
      int acc[8] = {0, 0, 0, 0, 0, 0, 0, 0};
#pragma unroll
      for (int w = 0; w < CWn; ++w) {
        const uint32_t xw = x[w];
#pragma unroll
        for (int q = 0; q < 8; ++q)
          acc[q] += __popc(xw ^ wrow[q * CWn + w]);
      }
#pragma unroll
      for (int q = 0; q < 8; ++q) {
        const float v = (float)(Cc - 2 * acc[q]);
        const uint64_t m = __ballot(v > thr2n[o + q]);
        if ((lane & 31) == 0)
          Yout[((size_t)b * TWn + (t >> 5)) * Hn + o + q] = (uint32_t)(m >> lane);
      }
    }
  }
}

// ----------------------------------------------------------------------------
extern "C" void kernel_launch(void* const* d_in, const int* in_sizes, int n_in,
                              void* d_out, int out_size, void* d_ws, size_t ws_size,
                              hipStream_t stream)
{
  const float* x     = (const float*)d_in[0];
  const float* bn1g  = (const float*)d_in[1];
  const float* bn1b  = (const float*)d_in[2];
  const float* bn1m  = (const float*)d_in[3];
  const float* bn1v  = (const float*)d_in[4];
  const float* w1    = (const float*)d_in[5];
  const float* bn2g  = (const float*)d_in[6];
  const float* bn2b  = (const float*)d_in[7];
  const float* bn2m  = (const float*)d_in[8];
  const float* bn2v  = (const float*)d_in[9];
  const float* dww   = (const float*)d_in[10];
  const float* bn3g  = (const float*)d_in[11];
  const float* bn3b  = (const float*)d_in[12];
  const float* bn3m  = (const float*)d_in[13];
  const float* bn3v  = (const float*)d_in[14];
  const float* w2    = (const float*)d_in[15];
  float* out = (float*)d_out;

  // workspace carve-up (~10.6 MB total)
  char* ws = (char*)d_ws;
  uint32_t* Xp  = (uint32_t*)(ws);                        // 2 MB (prologue only)
  uint32_t* Ya  = (uint32_t*)(ws + (2u  << 20));          // 4 MB  [b][tw][h]
  uint32_t* Yb  = (uint32_t*)(ws + (6u  << 20));          // 4 MB  [b][tw][h]
  uint32_t* W1p = (uint32_t*)(ws + (10u << 20));          // 128 KB
  uint32_t* W2p = (uint32_t*)(ws + (10u << 20) + (128u << 10)); // 128 KB
  float*    thr1 = (float*)(ws + (10u << 20) + (256u << 10));
  float*    thr2 = thr1 + 8 * Cc;
  float*    thr3 = thr2 + 8 * Hn;
  uint32_t* dws  = (uint32_t*)(thr3 + 8 * Hn);

  setup_kernel<<<256, 256, 0, stream>>>(bn1g, bn1b, bn1m, bn1v, w1,
                                        bn2g, bn2b, bn2m, bn2v, dww,
                                        bn3g, bn3b, bn3m, bn3v, w2,
                                        thr1, thr2, thr3, dws, W1p, W2p);

  k1_pack <<<2048,  256, 0, stream>>>(x, thr1, Xp);
  k2_gemm1<<<16384, 256, 0, stream>>>(Xp, W1p, thr2, Ya);

  for (int i = 0; i < 8; ++i) {
    const float* rin = (i == 0) ? x : out;
    const int inext = (i < 7) ? i + 1 : 7;
    const uint32_t* Yin  = (i & 1) ? Yb : Ya;
    uint32_t*       Yout = (i & 1) ? Ya : Yb;
    k_iter<<<1024, 512, 0, stream>>>(Yin, dws + i * Hn, thr3 + i * Hn,
                                     W2p + i * Cc * HWn, rin, out,
                                     thr1 + inext * Cc, W1p + inext * Hn * CWn,
                                     thr2 + inext * Hn, Yout,
                                     1 << i, (i < 7) ? 1 : 0);
  }
}